// Round 9
// baseline (285.191 us; speedup 1.0000x reference)
//
#include <hip/hip_runtime.h>
#include <stdint.h>

// Weighted MSE loss:
//   bin i s.t. edge[i] < t <= edge[i+1]  -> weight[i]; outside -> 0
//   loss = sum(w * (p - t)^2) / sum(weights)
// R7: forced MLP via inline-asm loads. R2/R6 proved hipcc serializes named
// loads (VGPR=36 for 16 float4s -> ~2 in flight). Here: 8 global_load_dwordx4
// issued in ONE asm block (early-clobber outs -> 8 concurrent), staged
// s_waitcnt vmcnt(6/4/2/0) + sched_barrier(0) so compute overlaps load tail.
// Flat structure from R5 (best so far): 8192 blocks x 16KB window/array,
// plain partial store, 1-block finish kernel.

typedef float f32x4 __attribute__((ext_vector_type(4)));

#define BLOCK 256
#define F4PT 4                    // float4s per thread per array
#define F4PB (BLOCK * F4PT)       // 1024 float4s per array per block

__device__ __forceinline__ float wmse_elem(float p, float t,
                                           float e0, float e1, float e2,
                                           float e3, float e4, float e5,
                                           float w0, float w1, float w2,
                                           float w3, float w4) {
    float w = 0.0f;
    w = (t > e0 && t <= e1) ? w0 : w;
    w = (t > e1 && t <= e2) ? w1 : w;
    w = (t > e2 && t <= e3) ? w2 : w;
    w = (t > e3 && t <= e4) ? w3 : w;
    w = (t > e4 && t <= e5) ? w4 : w;
    float d = p - t;
    return w * d * d;
}

#define WMSE4V(p, t) (                                                         \
    wmse_elem((p)[0], (t)[0], e0, e1, e2, e3, e4, e5, w0, w1, w2, w3, w4) +    \
    wmse_elem((p)[1], (t)[1], e0, e1, e2, e3, e4, e5, w0, w1, w2, w3, w4) +    \
    wmse_elem((p)[2], (t)[2], e0, e1, e2, e3, e4, e5, w0, w1, w2, w3, w4) +    \
    wmse_elem((p)[3], (t)[3], e0, e1, e2, e3, e4, e5, w0, w1, w2, w3, w4))

__global__ __launch_bounds__(256) void WeightedMSELoss_60335700574782_kernel(
    const float* __restrict__ pred, const float* __restrict__ targ,
    const float* __restrict__ edge, const float* __restrict__ weights,
    float* __restrict__ partial) {
    const float e0 = edge[0], e1 = edge[1], e2 = edge[2];
    const float e3 = edge[3], e4 = edge[4], e5 = edge[5];
    const float w0 = weights[0], w1 = weights[1], w2 = weights[2];
    const float w3 = weights[3], w4 = weights[4];

    const f32x4* __restrict__ p4 = (const f32x4*)pred;
    const f32x4* __restrict__ t4 = (const f32x4*)targ;
    const long long base = (long long)blockIdx.x * F4PB + threadIdx.x;

    const f32x4* pa = p4 + base;
    const f32x4* ta = t4 + base;

    // Issue all 8 loads back-to-back; early-clobber outputs keep all 8
    // destinations (32 VGPRs) live -> 8 KB in flight per wave.
    f32x4 P0, P1, P2, P3, T0, T1, T2, T3;
    asm volatile(
        "global_load_dwordx4 %0, %8, off\n\t"
        "global_load_dwordx4 %4, %12, off\n\t"
        "global_load_dwordx4 %1, %9, off\n\t"
        "global_load_dwordx4 %5, %13, off\n\t"
        "global_load_dwordx4 %2, %10, off\n\t"
        "global_load_dwordx4 %6, %14, off\n\t"
        "global_load_dwordx4 %3, %11, off\n\t"
        "global_load_dwordx4 %7, %15, off"
        : "=&v"(P0), "=&v"(P1), "=&v"(P2), "=&v"(P3),
          "=&v"(T0), "=&v"(T1), "=&v"(T2), "=&v"(T3)
        : "v"(pa), "v"(pa + 256), "v"(pa + 512), "v"(pa + 768),
          "v"(ta), "v"(ta + 256), "v"(ta + 512), "v"(ta + 768));

    // Staged consumption: compute overlaps the load tail.
    float acc0, acc1, acc2, acc3;
    asm volatile("s_waitcnt vmcnt(6)" ::: "memory");
    __builtin_amdgcn_sched_barrier(0);
    acc0 = WMSE4V(P0, T0);
    asm volatile("s_waitcnt vmcnt(4)" ::: "memory");
    __builtin_amdgcn_sched_barrier(0);
    acc1 = WMSE4V(P1, T1);
    asm volatile("s_waitcnt vmcnt(2)" ::: "memory");
    __builtin_amdgcn_sched_barrier(0);
    acc2 = WMSE4V(P2, T2);
    asm volatile("s_waitcnt vmcnt(0)" ::: "memory");
    __builtin_amdgcn_sched_barrier(0);
    acc3 = WMSE4V(P3, T3);

    float acc = (acc0 + acc1) + (acc2 + acc3);

    // wave64 reduce
    #pragma unroll
    for (int off = 32; off > 0; off >>= 1)
        acc += __shfl_down(acc, off, 64);

    __shared__ float smem[4];  // 256 threads = 4 waves
    const int lane = threadIdx.x & 63;
    const int wid = threadIdx.x >> 6;
    if (lane == 0) smem[wid] = acc;
    __syncthreads();
    if (threadIdx.x == 0)
        partial[blockIdx.x] = smem[0] + smem[1] + smem[2] + smem[3];
}

__global__ __launch_bounds__(256) void wmse_finish_kernel(
    const float* __restrict__ partial, int nparts,
    const float* __restrict__ pred, const float* __restrict__ targ,
    const float* __restrict__ edge, const float* __restrict__ weights,
    float* __restrict__ out, long long tail_start, long long n) {
    const float e0 = edge[0], e1 = edge[1], e2 = edge[2];
    const float e3 = edge[3], e4 = edge[4], e5 = edge[5];
    const float w0 = weights[0], w1 = weights[1], w2 = weights[2];
    const float w3 = weights[3], w4 = weights[4];
    const float inv_wsum = 1.0f / (w0 + w1 + w2 + w3 + w4);

    float acc = 0.0f;
    for (int i = threadIdx.x; i < nparts; i += blockDim.x)
        acc += partial[i];

    // remainder elements not covered by full blocks (none at this N)
    for (long long j = tail_start + threadIdx.x; j < n; j += blockDim.x)
        acc += wmse_elem(pred[j], targ[j], e0, e1, e2, e3, e4, e5, w0, w1, w2, w3, w4);

    #pragma unroll
    for (int off = 32; off > 0; off >>= 1)
        acc += __shfl_down(acc, off, 64);

    __shared__ float smem[4];
    const int lane = threadIdx.x & 63;
    const int wid = threadIdx.x >> 6;
    if (lane == 0) smem[wid] = acc;
    __syncthreads();
    if (threadIdx.x == 0)
        out[0] = (smem[0] + smem[1] + smem[2] + smem[3]) * inv_wsum;
}

extern "C" void kernel_launch(void* const* d_in, const int* in_sizes, int n_in,
                              void* d_out, int out_size, void* d_ws, size_t ws_size,
                              hipStream_t stream) {
    const float* pred    = (const float*)d_in[0];
    const float* targ    = (const float*)d_in[1];
    const float* weights = (const float*)d_in[2];
    const float* edge    = (const float*)d_in[3];
    float* out = (float*)d_out;
    float* partial = (float*)d_ws;    // one float per block; written before read
    const long long n = (long long)in_sizes[0];
    const long long n4 = n >> 2;

    const int grid = (int)(n4 / F4PB);                  // 8192 at this N
    const long long tail_start = (long long)grid * F4PB * 4;

    if (grid > 0) {
        WeightedMSELoss_60335700574782_kernel<<<grid, BLOCK, 0, stream>>>(
            pred, targ, edge, weights, partial);
    }
    wmse_finish_kernel<<<1, BLOCK, 0, stream>>>(
        partial, grid, pred, targ, edge, weights, out, tail_start, n);
}

// Round 11
// 257.192 us; speedup vs baseline: 1.1089x; 1.1089x over previous
//
#include <hip/hip_runtime.h>

// Weighted MSE loss:
//   bin i s.t. edge[i] < t <= edge[i+1]  -> weight[i]; outside -> 0
//   loss = sum(w * (p - t)^2) / sum(weights)
// R10: nontemporal loads. Evidence: R7 forced 8-deep MLP -> no change; warm-L3
// replay (FETCH~0) -> same 99us. Read path pinned at ~2.9 TB/s regardless of
// source/ILP/geometry -> suspect cache-allocation on load return caps at
// ~5 B/cyc/CU. __builtin_nontemporal_load sets nt bits (no line allocation).
// Also: cascade weight select (edges sorted: t>e2 => t>e1), 12 ops/elem.
// Flat R5 structure, 2 float4/thread/array, hashed-atomic partials (proven).

#define NSLOTS 2048
#define BLOCK 256
#define F4PT 2
#define F4PB (BLOCK * F4PT)   // 512 float4 per array per block

typedef float f32x4 __attribute__((ext_vector_type(4)));

__global__ void wmse_zero_ws(float* __restrict__ ws) {
    ws[blockIdx.x * blockDim.x + threadIdx.x] = 0.0f;   // 8 x 256 = 2048
}

__device__ __forceinline__ float wmse_elem(float p, float t,
                                           float e0, float e1, float e2,
                                           float e3, float e4, float e5,
                                           float w0, float w1, float w2,
                                           float w3, float w4) {
    // cascade: edges sorted, so later conditions override earlier ones
    float w = w0;
    w = (t > e1) ? w1 : w;
    w = (t > e2) ? w2 : w;
    w = (t > e3) ? w3 : w;
    w = (t > e4) ? w4 : w;
    w = (t > e0 && t <= e5) ? w : 0.0f;
    float d = p - t;
    return w * d * d;
}

#define WMSE4V(p, t) (                                                         \
    wmse_elem((p)[0], (t)[0], e0, e1, e2, e3, e4, e5, w0, w1, w2, w3, w4) +    \
    wmse_elem((p)[1], (t)[1], e0, e1, e2, e3, e4, e5, w0, w1, w2, w3, w4) +    \
    wmse_elem((p)[2], (t)[2], e0, e1, e2, e3, e4, e5, w0, w1, w2, w3, w4) +    \
    wmse_elem((p)[3], (t)[3], e0, e1, e2, e3, e4, e5, w0, w1, w2, w3, w4))

__global__ __launch_bounds__(256) void WeightedMSELoss_60335700574782_kernel(
    const float* __restrict__ pred, const float* __restrict__ targ,
    const float* __restrict__ edge, const float* __restrict__ weights,
    float* __restrict__ partial) {
    const float e0 = edge[0], e1 = edge[1], e2 = edge[2];
    const float e3 = edge[3], e4 = edge[4], e5 = edge[5];
    const float w0 = weights[0], w1 = weights[1], w2 = weights[2];
    const float w3 = weights[3], w4 = weights[4];

    const f32x4* __restrict__ p4 = (const f32x4*)pred;
    const f32x4* __restrict__ t4 = (const f32x4*)targ;
    const long long base = (long long)blockIdx.x * F4PB + threadIdx.x;

    // nontemporal: no cache-line allocation on the read path
    f32x4 P0 = __builtin_nontemporal_load(p4 + base);
    f32x4 T0 = __builtin_nontemporal_load(t4 + base);
    f32x4 P1 = __builtin_nontemporal_load(p4 + base + 256);
    f32x4 T1 = __builtin_nontemporal_load(t4 + base + 256);

    float acc0 = WMSE4V(P0, T0);
    float acc1 = WMSE4V(P1, T1);
    float acc = acc0 + acc1;

    // wave64 reduce
    #pragma unroll
    for (int off = 32; off > 0; off >>= 1)
        acc += __shfl_down(acc, off, 64);

    __shared__ float smem[4];  // 256 threads = 4 waves
    const int lane = threadIdx.x & 63;
    const int wid = threadIdx.x >> 6;
    if (lane == 0) smem[wid] = acc;
    __syncthreads();
    if (threadIdx.x == 0) {
        float bsum = smem[0] + smem[1] + smem[2] + smem[3];
        atomicAdd(&partial[blockIdx.x & (NSLOTS - 1)], bsum);
    }
}

__global__ __launch_bounds__(256) void wmse_finish_kernel(
    const float* __restrict__ partial,
    const float* __restrict__ pred, const float* __restrict__ targ,
    const float* __restrict__ edge, const float* __restrict__ weights,
    float* __restrict__ out, long long tail_start, long long n) {
    const float e0 = edge[0], e1 = edge[1], e2 = edge[2];
    const float e3 = edge[3], e4 = edge[4], e5 = edge[5];
    const float w0 = weights[0], w1 = weights[1], w2 = weights[2];
    const float w3 = weights[3], w4 = weights[4];
    const float inv_wsum = 1.0f / (w0 + w1 + w2 + w3 + w4);

    float acc = 0.0f;
    for (int i = threadIdx.x; i < NSLOTS; i += blockDim.x)
        acc += partial[i];

    // remainder elements not covered by full blocks (none at this N)
    for (long long j = tail_start + threadIdx.x; j < n; j += blockDim.x)
        acc += wmse_elem(pred[j], targ[j], e0, e1, e2, e3, e4, e5, w0, w1, w2, w3, w4);

    #pragma unroll
    for (int off = 32; off > 0; off >>= 1)
        acc += __shfl_down(acc, off, 64);

    __shared__ float smem[4];
    const int lane = threadIdx.x & 63;
    const int wid = threadIdx.x >> 6;
    if (lane == 0) smem[wid] = acc;
    __syncthreads();
    if (threadIdx.x == 0)
        out[0] = (smem[0] + smem[1] + smem[2] + smem[3]) * inv_wsum;
}

extern "C" void kernel_launch(void* const* d_in, const int* in_sizes, int n_in,
                              void* d_out, int out_size, void* d_ws, size_t ws_size,
                              hipStream_t stream) {
    const float* pred    = (const float*)d_in[0];
    const float* targ    = (const float*)d_in[1];
    const float* weights = (const float*)d_in[2];
    const float* edge    = (const float*)d_in[3];
    float* out = (float*)d_out;
    float* partial = (float*)d_ws;    // NSLOTS floats = 8 KB scratch
    const long long n = (long long)in_sizes[0];
    const long long n4 = n >> 2;

    wmse_zero_ws<<<NSLOTS / 256, 256, 0, stream>>>(partial);

    const int grid = (int)(n4 / F4PB);                  // 16384 at this N
    const long long tail_start = (long long)grid * F4PB * 4;

    if (grid > 0) {
        WeightedMSELoss_60335700574782_kernel<<<grid, BLOCK, 0, stream>>>(
            pred, targ, edge, weights, partial);
    }
    wmse_finish_kernel<<<1, BLOCK, 0, stream>>>(
        partial, pred, targ, edge, weights, out, tail_start, n);
}